// Round 1
// baseline (4935.819 us; speedup 1.0000x reference)
//
#include <hip/hip_runtime.h>
#include <cstddef>

#define T_STEPS 90
#define BT      2048
#define NXV     144
#define HV      128
#define NZV     128
#define M1V     300
#define M2V     200
#define G3      384   // 3*H
#define NB      8     // batch elements per workgroup
#define NTH     384   // threads per workgroup (6 waves)

__device__ __forceinline__ float fast_sigmoid(float v) {
    return 1.0f / (1.0f + __expf(-v));
}
__device__ __forceinline__ float fast_tanh(float v) {
    // tanh(x) = 1 - 2/(exp(2x)+1); saturates correctly at +/-inf
    return 1.0f - 2.0f / (__expf(2.0f * v) + 1.0f);
}

// dot of one weight row (length K, fp32, 16B-aligned) against LDS activations
// acts[k][b] (b minor, rows 32B). All lanes read the same LDS address per
// (k,b) -> broadcast, conflict-free. Accumulates NB batch dots in registers.
template<int K>
__device__ __forceinline__ void dot8(const float* __restrict__ w,
                                     const float (* __restrict__ acts)[NB],
                                     float acc[NB]) {
    const float4* __restrict__ w4 = reinterpret_cast<const float4*>(w);
    #pragma unroll 4
    for (int k4 = 0; k4 < K / 4; ++k4) {
        float4 wv = w4[k4];
        #pragma unroll
        for (int j = 0; j < 4; ++j) {
            float wj = (j == 0) ? wv.x : (j == 1) ? wv.y : (j == 2) ? wv.z : wv.w;
            const float* a = acts[4 * k4 + j];
            #pragma unroll
            for (int b = 0; b < NB; ++b) acc[b] = fmaf(wj, a[b], acc[b]);
        }
    }
}

__global__ void __launch_bounds__(NTH)
vae_fused(const float* __restrict__ x,
          const float* __restrict__ w_ih_e, const float* __restrict__ w_hh_e,
          const float* __restrict__ b_ih_e, const float* __restrict__ b_hh_e,
          const float* __restrict__ W1e, const float* __restrict__ b1e,
          const float* __restrict__ W2e, const float* __restrict__ b2e,
          const float* __restrict__ Wmu, const float* __restrict__ bmu,
          const float* __restrict__ Wlv, const float* __restrict__ blv,
          const float* __restrict__ w_ih_d, const float* __restrict__ w_hh_d,
          const float* __restrict__ b_ih_d, const float* __restrict__ b_hh_d,
          const float* __restrict__ W1d, const float* __restrict__ b1d,
          const float* __restrict__ W2d, const float* __restrict__ b2d,
          const float* __restrict__ Wo, const float* __restrict__ bo,
          float* __restrict__ out)
{
    // activations: k-major, batch-minor (32B rows -> 2x ds_read_b128 broadcast)
    __shared__ __align__(16) float xs [NXV][NB];   // x_t staging / decoder xp
    __shared__ __align__(16) float hs [HV ][NB];   // GRU hidden state
    __shared__ __align__(16) float m1s[M1V][NB];
    __shared__ __align__(16) float m2s[M2V][NB];
    __shared__ __align__(16) float zsh[NZV][NB];   // z = mu
    // gate exchange: b-major, neuron-minor (stride-1 across lanes, conflict-free)
    __shared__ __align__(16) float gig[NB][G3];
    __shared__ __align__(16) float ghg[NB][G3];

    const int tid   = threadIdx.x;
    const int bbase = blockIdx.x * NB;

    const size_t XREC_SZ = (size_t)T_STEPS * BT * NXV;
    const size_t MU_OFF  = XREC_SZ;
    const size_t LV_OFF  = XREC_SZ + (size_t)BT * NZV;

    // h0 = 0
    for (int i = tid; i < HV * NB; i += NTH) ((float*)hs)[i] = 0.0f;
    __syncthreads();

    // ================= encoder GRU over 90 steps =================
    for (int t = 0; t < T_STEPS; ++t) {
        // stage x_t tile (coalesced along k)
        for (int i = tid; i < NXV * NB; i += NTH) {
            int b = i / NXV, k = i - b * NXV;
            xs[k][b] = x[(size_t)t * (BT * NXV) + (size_t)(bbase + b) * NXV + k];
        }
        __syncthreads();
        {   // all 384 threads: one gate neuron each
            const int n = tid;
            float ai[NB], ah[NB];
            const float bi = b_ih_e[n], bh = b_hh_e[n];
            #pragma unroll
            for (int b = 0; b < NB; ++b) { ai[b] = bi; ah[b] = bh; }
            dot8<NXV>(w_ih_e + (size_t)n * NXV, xs, ai);
            dot8<HV >(w_hh_e + (size_t)n * HV,  hs, ah);
            #pragma unroll
            for (int b = 0; b < NB; ++b) { gig[b][n] = ai[b]; ghg[b][n] = ah[b]; }
        }
        __syncthreads();
        if (tid < HV) {   // GRU combine (PyTorch GRUCell: b_hh_n inside r*(...))
            const int j = tid;
            #pragma unroll
            for (int b = 0; b < NB; ++b) {
                float r  = fast_sigmoid(gig[b][j]          + ghg[b][j]);
                float zz = fast_sigmoid(gig[b][j + HV]     + ghg[b][j + HV]);
                float nn = fast_tanh   (gig[b][j + 2 * HV] + r * ghg[b][j + 2 * HV]);
                hs[j][b] = (1.0f - zz) * nn + zz * hs[j][b];
            }
        }
        __syncthreads();
    }

    // ================= encoder MLP + latent heads =================
    if (tid < M1V) {
        float acc[NB]; const float bb = b1e[tid];
        #pragma unroll
        for (int b = 0; b < NB; ++b) acc[b] = bb;
        dot8<HV>(W1e + (size_t)tid * HV, hs, acc);
        #pragma unroll
        for (int b = 0; b < NB; ++b) m1s[tid][b] = fast_tanh(acc[b]);
    }
    __syncthreads();
    if (tid < M2V) {
        float acc[NB]; const float bb = b2e[tid];
        #pragma unroll
        for (int b = 0; b < NB; ++b) acc[b] = bb;
        dot8<M1V>(W2e + (size_t)tid * M1V, m1s, acc);
        #pragma unroll
        for (int b = 0; b < NB; ++b) m2s[tid][b] = fast_tanh(acc[b]);
    }
    __syncthreads();
    if (tid < NZV) {
        float acc[NB]; const float bb = bmu[tid];
        #pragma unroll
        for (int b = 0; b < NB; ++b) acc[b] = bb;
        dot8<M2V>(Wmu + (size_t)tid * M2V, m2s, acc);
        #pragma unroll
        for (int b = 0; b < NB; ++b) {
            zsh[tid][b] = acc[b];
            out[MU_OFF + (size_t)(bbase + b) * NZV + tid] = acc[b];
        }
    } else if (tid < 2 * NZV) {
        const int n = tid - NZV;
        float acc[NB]; const float bb = blv[n];
        #pragma unroll
        for (int b = 0; b < NB; ++b) acc[b] = bb;
        dot8<M2V>(Wlv + (size_t)n * M2V, m2s, acc);
        #pragma unroll
        for (int b = 0; b < NB; ++b)
            out[LV_OFF + (size_t)(bbase + b) * NZV + n] = acc[b];
    }
    __syncthreads();

    // ================= decoder init =================
    // hd = 0; xp = x[0]; giz[n][b] = b_ih_d[n] + z . w_ih_d[n, 144:272]
    for (int i = tid; i < HV * NB; i += NTH) ((float*)hs)[i] = 0.0f;
    for (int i = tid; i < NXV * NB; i += NTH) {
        int b = i / NXV, k = i - b * NXV;
        xs[k][b] = x[(size_t)(bbase + b) * NXV + k];
    }
    float gz[NB];
    {
        const int n = tid;
        const float bb = b_ih_d[n];
        #pragma unroll
        for (int b = 0; b < NB; ++b) gz[b] = bb;
        dot8<NZV>(w_ih_d + (size_t)n * (NXV + NZV) + NXV, zsh, gz);
    }
    __syncthreads();

    // ================= decoder: 90 autoregressive steps =================
    for (int t = 0; t < T_STEPS; ++t) {
        {   // gates
            const int n = tid;
            float ai[NB], ah[NB];
            const float bh = b_hh_d[n];
            #pragma unroll
            for (int b = 0; b < NB; ++b) { ai[b] = gz[b]; ah[b] = bh; }
            dot8<NXV>(w_ih_d + (size_t)n * (NXV + NZV), xs, ai);
            dot8<HV >(w_hh_d + (size_t)n * HV,          hs, ah);
            #pragma unroll
            for (int b = 0; b < NB; ++b) { gig[b][n] = ai[b]; ghg[b][n] = ah[b]; }
        }
        __syncthreads();
        if (tid < HV) {
            const int j = tid;
            #pragma unroll
            for (int b = 0; b < NB; ++b) {
                float r  = fast_sigmoid(gig[b][j]          + ghg[b][j]);
                float zz = fast_sigmoid(gig[b][j + HV]     + ghg[b][j + HV]);
                float nn = fast_tanh   (gig[b][j + 2 * HV] + r * ghg[b][j + 2 * HV]);
                hs[j][b] = (1.0f - zz) * nn + zz * hs[j][b];
            }
        }
        __syncthreads();
        if (tid < M1V) {
            float acc[NB]; const float bb = b1d[tid];
            #pragma unroll
            for (int b = 0; b < NB; ++b) acc[b] = bb;
            dot8<HV>(W1d + (size_t)tid * HV, hs, acc);
            #pragma unroll
            for (int b = 0; b < NB; ++b) m1s[tid][b] = fast_tanh(acc[b]);
        }
        __syncthreads();
        if (tid < M2V) {
            float acc[NB]; const float bb = b2d[tid];
            #pragma unroll
            for (int b = 0; b < NB; ++b) acc[b] = bb;
            dot8<M1V>(W2d + (size_t)tid * M1V, m1s, acc);
            #pragma unroll
            for (int b = 0; b < NB; ++b) m2s[tid][b] = fast_tanh(acc[b]);
        }
        __syncthreads();
        if (tid < NXV) {
            float acc[NB]; const float bb = bo[tid];
            #pragma unroll
            for (int b = 0; b < NB; ++b) acc[b] = bb;
            dot8<M2V>(Wo + (size_t)tid * M2V, m2s, acc);
            #pragma unroll
            for (int b = 0; b < NB; ++b) {
                xs[tid][b] = acc[b];  // feedback
                out[(size_t)t * (BT * NXV) + (size_t)(bbase + b) * NXV + tid] = acc[b];
            }
        }
        __syncthreads();
    }
}

extern "C" void kernel_launch(void* const* d_in, const int* in_sizes, int n_in,
                              void* d_out, int out_size, void* d_ws, size_t ws_size,
                              hipStream_t stream) {
    (void)in_sizes; (void)n_in; (void)d_ws; (void)ws_size; (void)out_size;
    const float* p[23];
    for (int i = 0; i < 23; ++i) p[i] = (const float*)d_in[i];
    vae_fused<<<dim3(BT / NB), dim3(NTH), 0, stream>>>(
        p[0],  p[1],  p[2],  p[3],  p[4],  p[5],  p[6],  p[7],
        p[8],  p[9],  p[10], p[11], p[12], p[13], p[14], p[15],
        p[16], p[17], p[18], p[19], p[20], p[21], p[22],
        (float*)d_out);
}

// Round 2
// 3670.951 us; speedup vs baseline: 1.3446x; 1.3446x over previous
//
#include <hip/hip_runtime.h>
#include <cstddef>

#define T_STEPS 90
#define BT      2048
#define NXV     144
#define HV      128
#define NZV     128
#define M1V     300
#define M2V     200
#define G3      384   // 3*H
#define NB      8     // batch elements per workgroup
#define NTH     384   // threads per workgroup (6 waves)

// ---- transposed-weight layout in d_ws (float4 units) ----
// Wt4[k4 * N + n] = float4{ W[n][4k4 .. 4k4+3] }  -> lane n reads coalesced.
constexpr int K4_IHE  = NXV / 4;  // 36
constexpr int K4_HH   = HV  / 4;  // 32
constexpr int K4_W1   = HV  / 4;  // 32
constexpr int K4_W2   = M1V / 4;  // 75
constexpr int K4_HEAD = M2V / 4;  // 50
constexpr int K4_O    = M2V / 4;  // 50

constexpr int O_IHE  = 0;
constexpr int O_HHE  = O_IHE  + G3  * K4_IHE;
constexpr int O_W1E  = O_HHE  + G3  * K4_HH;
constexpr int O_W2E  = O_W1E  + M1V * K4_W1;
constexpr int O_MU   = O_W2E  + M2V * K4_W2;
constexpr int O_LV   = O_MU   + NZV * K4_HEAD;
constexpr int O_IHDX = O_LV   + NZV * K4_HEAD;
constexpr int O_IHDZ = O_IHDX + G3  * K4_IHE;
constexpr int O_HHD  = O_IHDZ + G3  * K4_HH;
constexpr int O_W1D  = O_HHD  + G3  * K4_HH;
constexpr int O_W2D  = O_W1D  + M1V * K4_W1;
constexpr int O_WO   = O_W2D  + M2V * K4_W2;

__device__ __forceinline__ float fast_sigmoid(float v) {
    return 1.0f / (1.0f + __expf(-v));
}
__device__ __forceinline__ float fast_tanh(float v) {
    return 1.0f - 2.0f / (__expf(2.0f * v) + 1.0f);
}
__device__ __forceinline__ float f4get(const float4& v, int j) {
    return j == 0 ? v.x : j == 1 ? v.y : j == 2 ? v.z : v.w;
}

// ---- prep: transpose all weight matrices into [k4][n] float4 tiles ----
__global__ void __launch_bounds__(256)
transpose_weights(const float* __restrict__ w_ih_e, const float* __restrict__ w_hh_e,
                  const float* __restrict__ W1e,    const float* __restrict__ W2e,
                  const float* __restrict__ Wmu,    const float* __restrict__ Wlv,
                  const float* __restrict__ w_ih_d, const float* __restrict__ w_hh_d,
                  const float* __restrict__ W1d,    const float* __restrict__ W2d,
                  const float* __restrict__ Wo,     float4* __restrict__ ws)
{
    const float* src; int N, K4, rs4, co4, off;
    switch (blockIdx.y) {
        case 0:  src = w_ih_e; N = G3;  K4 = K4_IHE;  rs4 = 36; co4 = 0;  off = O_IHE;  break;
        case 1:  src = w_hh_e; N = G3;  K4 = K4_HH;   rs4 = 32; co4 = 0;  off = O_HHE;  break;
        case 2:  src = W1e;    N = M1V; K4 = K4_W1;   rs4 = 32; co4 = 0;  off = O_W1E;  break;
        case 3:  src = W2e;    N = M2V; K4 = K4_W2;   rs4 = 75; co4 = 0;  off = O_W2E;  break;
        case 4:  src = Wmu;    N = NZV; K4 = K4_HEAD; rs4 = 50; co4 = 0;  off = O_MU;   break;
        case 5:  src = Wlv;    N = NZV; K4 = K4_HEAD; rs4 = 50; co4 = 0;  off = O_LV;   break;
        case 6:  src = w_ih_d; N = G3;  K4 = K4_IHE;  rs4 = 68; co4 = 0;  off = O_IHDX; break;
        case 7:  src = w_ih_d; N = G3;  K4 = K4_HH;   rs4 = 68; co4 = 36; off = O_IHDZ; break;
        case 8:  src = w_hh_d; N = G3;  K4 = K4_HH;   rs4 = 32; co4 = 0;  off = O_HHD;  break;
        case 9:  src = W1d;    N = M1V; K4 = K4_W1;   rs4 = 32; co4 = 0;  off = O_W1D;  break;
        case 10: src = W2d;    N = M2V; K4 = K4_W2;   rs4 = 75; co4 = 0;  off = O_W2D;  break;
        default: src = Wo;     N = NXV; K4 = K4_O;    rs4 = 50; co4 = 0;  off = O_WO;   break;
    }
    int i = blockIdx.x * 256 + threadIdx.x;
    if (i >= N * K4) return;
    int k4 = i / N, n = i - k4 * N;
    ws[off + i] = reinterpret_cast<const float4*>(src)[n * rs4 + co4 + k4];
}

// dot: lane-owned neuron n, transposed weights (coalesced), LDS-broadcast acts.
// CH float4s prefetched into registers before each FMA block for ILP.
template<int K4, int N, int CH>
__device__ __forceinline__ void dotT(const float4* __restrict__ wt, int n,
                                     const float (* __restrict__ acts)[NB],
                                     float acc[NB]) {
    const float4* __restrict__ p = wt + n;
    for (int c = 0; c < K4; c += CH) {
        float4 wv[CH];
        #pragma unroll
        for (int u = 0; u < CH; ++u) wv[u] = p[(size_t)(c + u) * N];
        #pragma unroll
        for (int u = 0; u < CH; ++u) {
            #pragma unroll
            for (int j = 0; j < 4; ++j) {
                float wj = f4get(wv[u], j);
                const float* a = acts[4 * (c + u) + j];
                #pragma unroll
                for (int b = 0; b < NB; ++b) acc[b] = fmaf(wj, a[b], acc[b]);
            }
        }
    }
}

__global__ void __launch_bounds__(NTH)
vae_fused(const float* __restrict__ x,
          const float* __restrict__ b_ih_e, const float* __restrict__ b_hh_e,
          const float* __restrict__ b1e,    const float* __restrict__ b2e,
          const float* __restrict__ bmu,    const float* __restrict__ blv,
          const float* __restrict__ b_ih_d, const float* __restrict__ b_hh_d,
          const float* __restrict__ b1d,    const float* __restrict__ b2d,
          const float* __restrict__ bo,
          const float4* __restrict__ ws,
          float* __restrict__ out)
{
    // activations: k-major, batch-minor (32B rows, broadcast reads)
    __shared__ __align__(16) float xs [2][NXV][NB];  // double-buffered x_t / decoder xp
    __shared__ __align__(16) float hs [HV ][NB];
    __shared__ __align__(16) float m1s[M1V][NB];
    __shared__ __align__(16) float m2s[M2V][NB];
    __shared__ __align__(16) float zsh[NZV][NB];
    // gate exchange: b-major, neuron-minor (stride-1, conflict-free)
    __shared__ __align__(16) float gig[NB][G3];
    __shared__ __align__(16) float ghg[NB][G3];

    const int tid   = threadIdx.x;
    const int bbase = blockIdx.x * NB;

    const size_t XREC_SZ = (size_t)T_STEPS * BT * NXV;
    const size_t MU_OFF  = XREC_SZ;
    const size_t LV_OFF  = XREC_SZ + (size_t)BT * NZV;

    // h0 = 0 ; stage x_0 into xs[0]
    for (int i = tid; i < HV * NB; i += NTH) ((float*)hs)[i] = 0.0f;
    #pragma unroll
    for (int u = 0; u < 3; ++u) {   // NXV*NB / NTH == 3
        int i = u * NTH + tid, b = i / NXV, k = i - b * NXV;
        xs[0][k][b] = x[(size_t)(bbase + b) * NXV + k];
    }
    __syncthreads();

    // ================= encoder GRU over 90 steps =================
    for (int t = 0; t < T_STEPS; ++t) {
        // prefetch x_{t+1} into registers (hidden under gate GEMM)
        float xpre[3];
        if (t + 1 < T_STEPS) {
            #pragma unroll
            for (int u = 0; u < 3; ++u) {
                int i = u * NTH + tid, b = i / NXV, k = i - b * NXV;
                xpre[u] = x[(size_t)(t + 1) * (BT * NXV) + (size_t)(bbase + b) * NXV + k];
            }
        }
        {   // gates: thread n owns gate neuron n for all NB batches
            const int n = tid;
            float ai[NB], ah[NB];
            const float bi = b_ih_e[n], bh = b_hh_e[n];
            #pragma unroll
            for (int b = 0; b < NB; ++b) { ai[b] = bi; ah[b] = bh; }
            dotT<K4_IHE, G3, 6>(ws + O_IHE, n, xs[t & 1], ai);
            dotT<K4_HH,  G3, 8>(ws + O_HHE, n, hs,        ah);
            #pragma unroll
            for (int b = 0; b < NB; ++b) { gig[b][n] = ai[b]; ghg[b][n] = ah[b]; }
        }
        if (t + 1 < T_STEPS) {
            #pragma unroll
            for (int u = 0; u < 3; ++u) {
                int i = u * NTH + tid, b = i / NXV, k = i - b * NXV;
                xs[(t + 1) & 1][k][b] = xpre[u];
            }
        }
        __syncthreads();
        if (tid < HV) {   // GRU combine (PyTorch: b_hh_n inside r*(...))
            const int j = tid;
            #pragma unroll
            for (int b = 0; b < NB; ++b) {
                float r  = fast_sigmoid(gig[b][j]          + ghg[b][j]);
                float zz = fast_sigmoid(gig[b][j + HV]     + ghg[b][j + HV]);
                float nn = fast_tanh   (gig[b][j + 2 * HV] + r * ghg[b][j + 2 * HV]);
                hs[j][b] = (1.0f - zz) * nn + zz * hs[j][b];
            }
        }
        __syncthreads();
    }

    // ================= encoder MLP + latent heads =================
    if (tid < M1V) {
        float acc[NB]; const float bb = b1e[tid];
        #pragma unroll
        for (int b = 0; b < NB; ++b) acc[b] = bb;
        dotT<K4_W1, M1V, 8>(ws + O_W1E, tid, hs, acc);
        #pragma unroll
        for (int b = 0; b < NB; ++b) m1s[tid][b] = fast_tanh(acc[b]);
    }
    __syncthreads();
    if (tid < M2V) {
        float acc[NB]; const float bb = b2e[tid];
        #pragma unroll
        for (int b = 0; b < NB; ++b) acc[b] = bb;
        dotT<K4_W2, M2V, 5>(ws + O_W2E, tid, m1s, acc);
        #pragma unroll
        for (int b = 0; b < NB; ++b) m2s[tid][b] = fast_tanh(acc[b]);
    }
    __syncthreads();
    if (tid < NZV) {
        float acc[NB]; const float bb = bmu[tid];
        #pragma unroll
        for (int b = 0; b < NB; ++b) acc[b] = bb;
        dotT<K4_HEAD, NZV, 5>(ws + O_MU, tid, m2s, acc);
        #pragma unroll
        for (int b = 0; b < NB; ++b) {
            zsh[tid][b] = acc[b];
            out[MU_OFF + (size_t)(bbase + b) * NZV + tid] = acc[b];
        }
    } else if (tid < 2 * NZV) {
        const int n = tid - NZV;
        float acc[NB]; const float bb = blv[n];
        #pragma unroll
        for (int b = 0; b < NB; ++b) acc[b] = bb;
        dotT<K4_HEAD, NZV, 5>(ws + O_LV, n, m2s, acc);
        #pragma unroll
        for (int b = 0; b < NB; ++b)
            out[LV_OFF + (size_t)(bbase + b) * NZV + n] = acc[b];
    }
    __syncthreads();

    // ================= decoder init =================
    for (int i = tid; i < HV * NB; i += NTH) ((float*)hs)[i] = 0.0f;
    #pragma unroll
    for (int u = 0; u < 3; ++u) {
        int i = u * NTH + tid, b = i / NXV, k = i - b * NXV;
        xs[0][k][b] = x[(size_t)(bbase + b) * NXV + k];
    }
    float gz[NB];
    {   // time-invariant z-contribution + b_ih_d
        const float bb = b_ih_d[tid];
        #pragma unroll
        for (int b = 0; b < NB; ++b) gz[b] = bb;
        dotT<K4_HH, G3, 8>(ws + O_IHDZ, tid, zsh, gz);
    }
    __syncthreads();

    // ================= decoder: 90 autoregressive steps =================
    for (int t = 0; t < T_STEPS; ++t) {
        {   // gates
            const int n = tid;
            float ai[NB], ah[NB];
            const float bh = b_hh_d[n];
            #pragma unroll
            for (int b = 0; b < NB; ++b) { ai[b] = gz[b]; ah[b] = bh; }
            dotT<K4_IHE, G3, 6>(ws + O_IHDX, n, xs[0], ai);
            dotT<K4_HH,  G3, 8>(ws + O_HHD,  n, hs,    ah);
            #pragma unroll
            for (int b = 0; b < NB; ++b) { gig[b][n] = ai[b]; ghg[b][n] = ah[b]; }
        }
        __syncthreads();
        if (tid < HV) {
            const int j = tid;
            #pragma unroll
            for (int b = 0; b < NB; ++b) {
                float r  = fast_sigmoid(gig[b][j]          + ghg[b][j]);
                float zz = fast_sigmoid(gig[b][j + HV]     + ghg[b][j + HV]);
                float nn = fast_tanh   (gig[b][j + 2 * HV] + r * ghg[b][j + 2 * HV]);
                hs[j][b] = (1.0f - zz) * nn + zz * hs[j][b];
            }
        }
        __syncthreads();
        if (tid < M1V) {
            float acc[NB]; const float bb = b1d[tid];
            #pragma unroll
            for (int b = 0; b < NB; ++b) acc[b] = bb;
            dotT<K4_W1, M1V, 8>(ws + O_W1D, tid, hs, acc);
            #pragma unroll
            for (int b = 0; b < NB; ++b) m1s[tid][b] = fast_tanh(acc[b]);
        }
        __syncthreads();
        if (tid < M2V) {
            float acc[NB]; const float bb = b2d[tid];
            #pragma unroll
            for (int b = 0; b < NB; ++b) acc[b] = bb;
            dotT<K4_W2, M2V, 5>(ws + O_W2D, tid, m1s, acc);
            #pragma unroll
            for (int b = 0; b < NB; ++b) m2s[tid][b] = fast_tanh(acc[b]);
        }
        __syncthreads();
        if (tid < NXV) {
            float acc[NB]; const float bb = bo[tid];
            #pragma unroll
            for (int b = 0; b < NB; ++b) acc[b] = bb;
            dotT<K4_O, NXV, 5>(ws + O_WO, tid, m2s, acc);
            #pragma unroll
            for (int b = 0; b < NB; ++b) {
                xs[0][tid][b] = acc[b];  // autoregressive feedback
                out[(size_t)t * (BT * NXV) + (size_t)(bbase + b) * NXV + tid] = acc[b];
            }
        }
        __syncthreads();
    }
}

extern "C" void kernel_launch(void* const* d_in, const int* in_sizes, int n_in,
                              void* d_out, int out_size, void* d_ws, size_t ws_size,
                              hipStream_t stream) {
    (void)in_sizes; (void)n_in; (void)ws_size; (void)out_size;
    const float* p[23];
    for (int i = 0; i < 23; ++i) p[i] = (const float*)d_in[i];
    float4* ws = (float4*)d_ws;

    // 12 sections, max 15000 float4 elems each -> 59 blocks of 256
    transpose_weights<<<dim3(59, 12), dim3(256), 0, stream>>>(
        p[1], p[2], p[5], p[7], p[9], p[11], p[13], p[14], p[17], p[19], p[21], ws);

    vae_fused<<<dim3(BT / NB), dim3(NTH), 0, stream>>>(
        p[0],                      // x
        p[3],  p[4],               // b_ih_e, b_hh_e
        p[6],  p[8],               // b1e, b2e
        p[10], p[12],              // bmu, blv
        p[15], p[16],              // b_ih_d, b_hh_d
        p[18], p[20],              // b1d, b2d
        p[22],                     // bo
        ws, (float*)d_out);
}